// Round 4
// baseline (24.170 us; speedup 1.0000x reference)
//
#include <hip/hip_runtime.h>
#include <stdint.h>

// ACOLayer: reproduce JAX's sampling exactly.
//   u = jax.random.uniform(key(42), (32, 4096, 16), f32)
//   idx[b,i,a] = searchsorted(cdf_row_i, u[b,i,a]) clamped; -1 where a >= x[b,i]
// RNG: jax_threefry_partitionable=True stream:
//   bits[i] = o0 ^ o1, (o0,o1) = threefry2x32(key=(0,42), counter=(0, i))
//   u = bitcast((bits>>9)|0x3f800000) - 1.0f
// Search: unnormalized cumsum, target u*total; accelerated by a 512-entry
// equi-probability bucket table built by inversion (scatter), then a short
// data-dependent binary search within [btab[k], btab[k+1]].

#define N_IN    4096
#define N_OUT   4096
#define BS      32
#define MAX_A   16
#define THREADS 256
#define HALF    1048576u  /* 16 * N_IN * MAX_A */
#define BUCKETS 512

// pad +4 floats per 64: breaks power-of-2 bank strides, keeps 16-chunks contiguous
__device__ __forceinline__ int padi(int j) { return j + ((j >> 6) << 2); }

__device__ __forceinline__ uint32_t rotl32(uint32_t x, uint32_t r) {
    return (x << r) | (x >> (32u - r));
}

// Threefry-2x32, 20 rounds, key (0, 42) — jax.random.key(42)
__device__ __forceinline__ void threefry2x32_42(uint32_t x0, uint32_t x1,
                                                uint32_t& o0, uint32_t& o1) {
    const uint32_t k0 = 0u, k1 = 42u;
    const uint32_t k2 = k0 ^ k1 ^ 0x1BD11BDAu;
    x0 += k0; x1 += k1;
#define TF_R(r) { x0 += x1; x1 = rotl32(x1, (r)); x1 ^= x0; }
    TF_R(13) TF_R(15) TF_R(26) TF_R(6)
    x0 += k1; x1 += k2 + 1u;
    TF_R(17) TF_R(29) TF_R(16) TF_R(24)
    x0 += k2; x1 += k0 + 2u;
    TF_R(13) TF_R(15) TF_R(26) TF_R(6)
    x0 += k0; x1 += k1 + 3u;
    TF_R(17) TF_R(29) TF_R(16) TF_R(24)
    x0 += k1; x1 += k2 + 4u;
    TF_R(13) TF_R(15) TF_R(26) TF_R(6)
    x0 += k2; x1 += k0 + 5u;
#undef TF_R
    o0 = x0; o1 = x1;
}

__device__ __forceinline__ float bits_to_uniform(uint32_t b) {
    uint32_t f = (b >> 9) | 0x3f800000u;
    float r;
    __builtin_memcpy(&r, &f, 4);
    return r - 1.0f;
}

__global__ __launch_bounds__(THREADS)
void aco_sample_kernel(const int* __restrict__ x,
                       const float* __restrict__ w,
                       int* __restrict__ out) {
    __shared__ float cdf[N_OUT + (N_OUT >> 4)];  // 17408 B, padded
    __shared__ int   btab[BUCKETS + 1];          // 2052 B
    __shared__ float wsum[4];
    __shared__ int   xc[BS];

    const int row  = blockIdx.x;
    const int t    = threadIdx.x;
    const int lane = t & 63;
    const int wid  = t >> 6;

    // ---- stage 16 weights directly into registers (4x float4) ----
    const float4* wrow = (const float4*)(w + (size_t)row * N_OUT);
    float4 v0 = wrow[t * 4 + 0];
    float4 v1 = wrow[t * 4 + 1];
    float4 v2 = wrow[t * 4 + 2];
    float4 v3 = wrow[t * 4 + 3];

    if (t < BS) xc[t] = x[t * N_IN + row];
    // init bucket table to top index (covers buckets above max crossing)
    btab[t]       = N_OUT - 1;
    btab[t + 256] = N_OUT - 1;
    if (t == 0) btab[BUCKETS] = N_OUT - 1;

    // ---- local inclusive scan of 16 values in registers ----
    float loc[16];
    {
        float s = 0.f;
        s += v0.x; loc[0]  = s;  s += v0.y; loc[1]  = s;
        s += v0.z; loc[2]  = s;  s += v0.w; loc[3]  = s;
        s += v1.x; loc[4]  = s;  s += v1.y; loc[5]  = s;
        s += v1.z; loc[6]  = s;  s += v1.w; loc[7]  = s;
        s += v2.x; loc[8]  = s;  s += v2.y; loc[9]  = s;
        s += v2.z; loc[10] = s;  s += v2.w; loc[11] = s;
        s += v3.x; loc[12] = s;  s += v3.y; loc[13] = s;
        s += v3.z; loc[14] = s;  s += v3.w; loc[15] = s;
    }
    const float my_total = loc[15];

    // ---- wave-level inclusive scan of per-thread totals ----
    float incl = my_total;
    #pragma unroll
    for (int d = 1; d < 64; d <<= 1) {
        float n = __shfl_up(incl, d, 64);
        if (lane >= d) incl += n;
    }
    if (lane == 63) wsum[wid] = incl;
    __syncthreads();   // barrier 1: wsum (and btab init) visible

    const float4 ws = *(const float4*)wsum;
    const float total = ws.x + ws.y + ws.z + ws.w;
    float wprefix = 0.f;
    if (wid > 0) wprefix += ws.x;
    if (wid > 1) wprefix += ws.y;
    if (wid > 2) wprefix += ws.z;
    const float chunk_prefix = wprefix + incl - my_total;

    // ---- write unnormalized cumsum to LDS (contiguous 16B chunks) ----
    float* cbase = &cdf[padi(t * 16)];
    {
        float4 a, b, c, d;
        a.x = chunk_prefix + loc[0];  a.y = chunk_prefix + loc[1];
        a.z = chunk_prefix + loc[2];  a.w = chunk_prefix + loc[3];
        b.x = chunk_prefix + loc[4];  b.y = chunk_prefix + loc[5];
        b.z = chunk_prefix + loc[6];  b.w = chunk_prefix + loc[7];
        c.x = chunk_prefix + loc[8];  c.y = chunk_prefix + loc[9];
        c.z = chunk_prefix + loc[10]; c.w = chunk_prefix + loc[11];
        d.x = chunk_prefix + loc[12]; d.y = chunk_prefix + loc[13];
        d.z = chunk_prefix + loc[14]; d.w = chunk_prefix + loc[15];
        ((float4*)cbase)[0] = a;
        ((float4*)cbase)[1] = b;
        ((float4*)cbase)[2] = c;
        ((float4*)cbase)[3] = d;
    }
    __syncthreads();   // barrier 2: full cdf visible

    // ---- build bucket table by inversion (scatter bucket crossings) ----
    // kprev must be bit-consistent with neighbor's last value -> read from LDS.
    const float scale = (float)BUCKETS / total;
    int kprev;
    if (t == 0) kprev = -1;
    else        kprev = (int)(cdf[padi(t * 16 - 1)] * scale);
    #pragma unroll
    for (int m = 0; m < 16; ++m) {
        int kj = (int)((chunk_prefix + loc[m]) * scale);  // same bits as LDS entry
        if (kj > BUCKETS) kj = BUCKETS;
        for (int b2 = kprev + 1; b2 <= kj; ++b2) btab[b2] = t * 16 + m;
        kprev = kj;
    }
    __syncthreads();   // barrier 3: btab complete

    // ---- two draws per thread: (b, row, a) and (b+16, row, a) ----
    const int b = t >> 4;
    const int a = t & 15;
    const uint32_t j0 = (uint32_t)(b * (N_IN * MAX_A) + row * MAX_A + a);
    const uint32_t j1 = j0 + HALF;

    uint32_t o0, o1, p0, p1;
    threefry2x32_42(0u, j0, o0, o1);
    threefry2x32_42(0u, j1, p0, p1);
    const float u0 = bits_to_uniform(o0 ^ o1);
    const float u1 = bits_to_uniform(p0 ^ p1);
    const float t0 = u0 * total;
    const float t1 = u1 * total;
    const int   k0 = (int)(u0 * (float)BUCKETS);   // 0..511 (u < 1)
    const int   k1 = (int)(u1 * (float)BUCKETS);

    int lo0 = btab[k0], hi0 = btab[k0 + 1];
    int lo1 = btab[k1], hi1 = btab[k1 + 1];

    // combined short binary searches (both draws overlap their LDS reads)
    while (lo0 < hi0 || lo1 < hi1) {
        if (lo0 < hi0) {
            int m = (lo0 + hi0) >> 1;
            if (cdf[padi(m)] < t0) lo0 = m + 1; else hi0 = m;
        }
        if (lo1 < hi1) {
            int m = (lo1 + hi1) >> 1;
            if (cdf[padi(m)] < t1) lo1 = m + 1; else hi1 = m;
        }
    }

    out[j0] = (a < xc[b])      ? lo0 : -1;
    out[j1] = (a < xc[b + 16]) ? lo1 : -1;
}

extern "C" void kernel_launch(void* const* d_in, const int* in_sizes, int n_in,
                              void* d_out, int out_size, void* d_ws, size_t ws_size,
                              hipStream_t stream) {
    // select inputs by size (robust to ordering):
    //   x: 32*4096 int32; weights: 4096*4096 f32
    const int*   x;
    const float* w;
    if (in_sizes[0] == BS * N_IN) { x = (const int*)d_in[0]; w = (const float*)d_in[1]; }
    else                          { x = (const int*)d_in[1]; w = (const float*)d_in[0]; }
    aco_sample_kernel<<<N_IN, THREADS, 0, stream>>>(x, w, (int*)d_out);
}